// Round 7
// baseline (374.459 us; speedup 1.0000x reference)
//
#include <hip/hip_runtime.h>

// N=1024, F_NODE=64, F_EDGE=32, F_IN=160.
// out[a,j] = sum_b gated(a,b,j);  gated = relu(Hp)*sigmoid(Ha)
// Hp[a,b,j] = A[a,b]*(H[a]·W[0:64,j] + H[b]·W[64:128,j] + E[a,b]·W[128:160,j]) + bias[j]
// A in {0,1}: A=0 pairs contribute g0[j]=relu(bias)*sigmoid(bias) (constant).
//
// R15 (this round): codegen-proof the E-stream register pipeline.
//  - R13/R14 kept showing the DEMOTION signature (VGPR=84, WRITE_SIZE
//    145-380MB scratch): the lambda-carried buffer arrays were not being
//    resolved to registers (un-inlined lambda => runtime `sub` => rule #20
//    via the back door). NOT a pressure spill (live ~130 < cap 168).
//  - Fix: NO lambdas, NO arrays for stream buffers. 8 named float4
//    variables + token-pasting macros; every access is a named scalar.
//    Bw/Ba/cw/ca stay as arrays indexed only by unrolled literals (these
//    were clean in R11).
//  - Unchanged from R14: stream E (16 uniform sub-chunks), A-mask from
//    LDS (exact 0/1), transient L2-hot H loads, (N-c1)*g0 constant path,
//    depth-2 pipeline, occ-3, setprio.
#define NN 1024
#define FN 64
#define FE 32
#define FIN 160

typedef __bf16 bf16x8 __attribute__((ext_vector_type(8)));
typedef short  short8 __attribute__((ext_vector_type(8)));
typedef float  f32x4  __attribute__((ext_vector_type(4)));

static __device__ __forceinline__ unsigned short f2b(float x){
    unsigned int u = __float_as_uint(x);
    unsigned int r = (u + 0x7fffu + ((u >> 16) & 1u)) >> 16;
    return (unsigned short)r;
}

static __device__ __forceinline__ float fast_sigmoid(float y){
    return __builtin_amdgcn_rcpf(1.0f + __expf(-y));
}

static __device__ __forceinline__ bf16x8 ldfrag(const unsigned short* p){
    return __builtin_bit_cast(bf16x8, *(const short8*)(p));
}

// pack two f32 -> (bf16 lo, bf16 hi) by truncation: one v_perm_b32
static __device__ __forceinline__ unsigned packtrunc(float lo, float hi){
    return __builtin_amdgcn_perm(__float_as_uint(hi), __float_as_uint(lo), 0x07060302u);
}

#define MF(A,B,C) __builtin_amdgcn_mfma_f32_16x16x32_bf16((A),(B),(C),0,0,0)

// blocks 0..63: H f32 -> Hb bf16 (1024x64); block 64/65: W/Wa -> Wt[j][k] bf16
__global__ void prep(const float* __restrict__ H, const float* __restrict__ W,
                     const float* __restrict__ Wa,
                     unsigned short* __restrict__ Hb,
                     unsigned short* __restrict__ WtE,
                     unsigned short* __restrict__ WtA){
    int bid = blockIdx.x, tid = threadIdx.x;
    if (bid < 64){
        int i = (bid*256 + tid)*4;
        float4 v = *(const float4*)(H + i);
        ushort4 o;
        o.x = f2b(v.x); o.y = f2b(v.y); o.z = f2b(v.z); o.w = f2b(v.w);
        *(ushort4*)(Hb + i) = o;
    } else {
        const float* src = (bid == 64) ? W : Wa;
        unsigned short* dst = (bid == 64) ? WtE : WtA;
        for (int idx = tid; idx < FIN*FN; idx += 256){
            int k = idx >> 6, j = idx & 63;
            dst[j*FIN + k] = f2b(src[idx]);
        }
    }
}

// Load one 64-row sub-chunk's E fragments into 4 NAMED float4 vars:
// X0,X1 = mt0 low/high 16B; Y0,Y1 = mt1 low/high 16B.
#define LOADSUB(su, X0, X1, Y0, Y1) do {                                   \
    int r0_ = (su)*64 + mh*32 + col;                                       \
    const float* ep0_ = E + ((size_t)a*NN + r0_)*FE + quad*8;              \
    const float* ep1_ = ep0_ + 16*FE;                                      \
    X0 = *(const float4*)(ep0_);                                           \
    X1 = *(const float4*)(ep0_ + 4);                                       \
    Y0 = *(const float4*)(ep1_);                                           \
    Y1 = *(const float4*)(ep1_ + 4);                                       \
} while(0)

// Compute one m-tile (mt) of one sub-chunk from named E vars X0,X1.
#define COMPMT(su, mt, X0, X1) do {                                        \
    int rr_ = (su)*64 + mh*32 + (mt)*16 + col;                             \
    bf16x8 hh0_ = ldfrag(Hb + rr_*FN + quad*8);                            \
    bf16x8 hh1_ = ldfrag(Hb + rr_*FN + 32 + quad*8);                       \
    int4 pk_;                                                              \
    pk_.x = (int)packtrunc((X0).x, (X0).y);                                \
    pk_.y = (int)packtrunc((X0).z, (X0).w);                                \
    pk_.z = (int)packtrunc((X1).x, (X1).y);                                \
    pk_.w = (int)packtrunc((X1).z, (X1).w);                                \
    bf16x8 ef_ = __builtin_bit_cast(bf16x8, pk_);                          \
    _Pragma("unroll")                                                      \
    for (int tl = 0; tl < 2; tl++){                                        \
        __builtin_amdgcn_s_setprio(1);                                     \
        f32x4 pw_ = MF(ef_, Bw[tl][2], MF(hh1_, Bw[tl][1],                 \
                     MF(hh0_, Bw[tl][0], cw[tl])));                        \
        f32x4 pa_ = MF(ef_, Ba[tl][2], MF(hh1_, Ba[tl][1],                 \
                     MF(hh0_, Ba[tl][0], ca[tl])));                        \
        __builtin_amdgcn_s_setprio(0);                                     \
        _Pragma("unroll")                                                  \
        for (int r4 = 0; r4 < 4; r4++){                                    \
            float am_ = amask[(su)*64 + mh*32 + (mt)*16 + quad*4 + r4];    \
            float f_  = fmaxf(pw_[r4], 0.f) * fast_sigmoid(pa_[r4]);       \
            acc[tl] += am_ * f_;                                           \
        }                                                                  \
    }                                                                      \
} while(0)

// One block per row a. Stream all 1024 b-rows of E[a] (16 sub-chunks of 64),
// mask the gate with A[a,b] from LDS, write out[a,:] directly including the
// (N-c1)*g0 constant term.
// 4 waves, wave=(half<<1)|mh: half -> j-tiles {2half,2half+1}, mh -> 32-row
// half of each 64-row sub-chunk.
// mfma_f32_16x16x32_bf16: A[m=lane&15][k=quad*8+i], B[k][n=lane&15],
// D: col=lane&15, row=quad*4+reg  [measured m89/m91].
__global__ __launch_bounds__(256, 3) void mga_fused(
    const float* __restrict__ A,
    const float* __restrict__ E,
    const unsigned short* __restrict__ Hb,
    const unsigned short* __restrict__ WtE, const unsigned short* __restrict__ WtA,
    const float* __restrict__ bias, float* __restrict__ out)
{
    int a    = blockIdx.x;
    int tid  = threadIdx.x;
    int wave = tid >> 6, lane = tid & 63;
    int col  = lane & 15, quad = lane >> 4;
    int half = wave >> 1, mh = wave & 1;

    __shared__ float amask[NN];            // A row as f32 (values are 0.0/1.0)
    __shared__ float red[16*FN];
    __shared__ int wsum[4];

    // ---- issue A-row load first: latency hides under B-frags + init MFMAs
    int b0 = wave*256 + lane*4;
    float4 av = *(const float4*)(A + (size_t)a*NN + b0);

    // Held B-frags: k-segs {64..96,96..128,128..160} x 2 j-tiles x 2 mats
    bf16x8 Bw[2][3], Ba[2][3];
    #pragma unroll
    for (int tl = 0; tl < 2; tl++){
        int n = (2*half + tl)*16 + col;
        #pragma unroll
        for (int sg = 0; sg < 3; sg++){
            Bw[tl][sg] = ldfrag(WtE + n*FIN + (sg+2)*32 + quad*8);
            Ba[tl][sg] = ldfrag(WtA + n*FIN + (sg+2)*32 + quad*8);
        }
    }

    // Upfront c-init = bias[j] + H[a]·W[0:64,j] via broadcast-A MFMAs
    bf16x8 ha0 = ldfrag(Hb + a*FN + quad*8);
    bf16x8 ha1 = ldfrag(Hb + a*FN + 32 + quad*8);
    f32x4 cw[2], ca[2];
    float acc[2] = {0.f, 0.f};
    #pragma unroll
    for (int tl = 0; tl < 2; tl++){
        int n = (2*half + tl)*16 + col;
        float bj = bias[n];
        f32x4 cb = {bj, bj, bj, bj};
        bf16x8 w0 = ldfrag(WtE + n*FIN + quad*8);
        bf16x8 w1 = ldfrag(WtE + n*FIN + 32 + quad*8);
        cw[tl] = MF(ha1, w1, MF(ha0, w0, cb));
        w0 = ldfrag(WtA + n*FIN + quad*8);
        w1 = ldfrag(WtA + n*FIN + 32 + quad*8);
        ca[tl] = MF(ha1, w1, MF(ha0, w0, cb));
    }

    // ---- publish A row to LDS + count nonzeros (no ordering needed)
    *(float4*)(amask + b0) = av;
    int m = 0;
    m += (av.x != 0.f) ? 1 : 0;
    m += (av.y != 0.f) ? 1 : 0;
    m += (av.z != 0.f) ? 1 : 0;
    m += (av.w != 0.f) ? 1 : 0;
    #pragma unroll
    for (int d = 1; d < 64; d <<= 1) m += __shfl_xor(m, d, 64);
    if (lane == 0) wsum[wave] = m;
    __syncthreads();                        // amask + wsum visible
    int c1 = wsum[0] + wsum[1] + wsum[2] + wsum[3];

    // ---- 8 NAMED in-flight E fragment registers (no arrays, no lambdas)
    float4 xA0, xA1, xB0, xB1;   // sub-chunk buffer 0: mt0 lo/hi, mt1 lo/hi
    float4 yA0, yA1, yB0, yB1;   // sub-chunk buffer 1

    LOADSUB(0, xA0, xA1, xB0, xB1);
    LOADSUB(1, yA0, yA1, yB0, yB1);
    for (int i = 0; i < 16; i += 2){
        COMPMT(i, 0, xA0, xA1);
        COMPMT(i, 1, xB0, xB1);
        if (i + 2 < 16) LOADSUB(i + 2, xA0, xA1, xB0, xB1);
        COMPMT(i + 1, 0, yA0, yA1);
        COMPMT(i + 1, 1, yB0, yB1);
        if (i + 3 < 16) LOADSUB(i + 3, yA0, yA1, yB0, yB1);
    }

    #pragma unroll
    for (int tl = 0; tl < 2; tl++)
        red[(wave*4 + quad)*FN + (2*half + tl)*16 + col] = acc[tl];
    __syncthreads();
    if (tid < FN){
        int rbase = (tid >= 32) ? 8 : 0;   // waves 0,1: j<32; waves 2,3: j>=32
        float sum = 0.f;
        #pragma unroll
        for (int r = 0; r < 8; r++) sum += red[(rbase + r)*FN + tid];
        float bj = bias[tid];
        float g0 = fmaxf(bj, 0.f) * fast_sigmoid(bj);
        out[(size_t)a*FN + tid] = sum + (float)(NN - c1) * g0;
    }
}

extern "C" void kernel_launch(void* const* d_in, const int* in_sizes, int n_in,
                              void* d_out, int out_size, void* d_ws, size_t ws_size,
                              hipStream_t stream) {
    const float* H    = (const float*)d_in[0];
    const float* A    = (const float*)d_in[1];
    const float* E    = (const float*)d_in[2];
    const float* W    = (const float*)d_in[3];
    const float* Wa   = (const float*)d_in[4];
    const float* bias = (const float*)d_in[5];
    float* out = (float*)d_out;

    unsigned short* Hb   = (unsigned short*)d_ws;         // 1024*64 bf16
    unsigned short* WtE  = Hb + NN*FN;                    // 64*160
    unsigned short* WtA  = WtE + FN*FIN;                  // 64*160

    prep     <<<dim3(66), dim3(256), 0, stream>>>(H, W, Wa, Hb, WtE, WtA);
    mga_fused<<<dim3(NN), dim3(256), 0, stream>>>(A, E, Hb, WtE, WtA, bias, out);
}

// Round 8
// 237.916 us; speedup vs baseline: 1.5739x; 1.5739x over previous
//
#include <hip/hip_runtime.h>

// N=1024, F_NODE=64, F_EDGE=32, F_IN=160.
// out[a,j] = sum_b gated(a,b,j);  gated = relu(Hp)*sigmoid(Ha)
// Hp[a,b,j] = A[a,b]*(H[a]·W[0:64,j] + H[b]·W[64:128,j] + E[a,b]·W[128:160,j]) + bias[j]
// A in {0,1}: A=0 pairs contribute g0[j]=relu(bias)*sigmoid(bias) (constant).
//
// R16 (this round): LDS-staged E stream via global_load_lds (T3 2-phase).
//  - R13/R14/R15 all hit the same scratch signature (VGPR=84, WRITE 145-380MB)
//    regardless of source spelling -> stop holding the E stream in VGPRs.
//    global_load_lds DMAs E tiles straight to LDS: held regs drop to
//    Bw/Ba/cw/ca (~66) + transients; nothing left to demote.
//  - 16 tiles x 64 rows x 32 f32 (8KB), double-buffered (16KB LDS).
//    One __syncthreads per tile (implicit vmcnt drain = m97 pattern);
//    next tile's stage issued BEFORE compute -> latency hides under MFMA.
//  - Conflict-free readback BY LAYOUT: stage-side per-lane global source
//    permutes 16B chunks into instruction order (m173 pattern), so each
//    ds_read_b128's 64 lanes read base+lane*16 -> 2 lanes/bank -> free.
//  - __launch_bounds__(256,4): 4 blocks/CU (VGPR cap 128, live ~110);
//    1024 blocks = exactly one round. setprio dropped (barrier-paced loop).
#define NN 1024
#define FN 64
#define FE 32
#define FIN 160

#pragma clang diagnostic ignored "-Waddress-space-conversion"

typedef __bf16 bf16x8 __attribute__((ext_vector_type(8)));
typedef short  short8 __attribute__((ext_vector_type(8)));
typedef float  f32x4  __attribute__((ext_vector_type(4)));
typedef __attribute__((address_space(1))) const unsigned int gu32;
typedef __attribute__((address_space(3))) unsigned int lu32;

static __device__ __forceinline__ unsigned short f2b(float x){
    unsigned int u = __float_as_uint(x);
    unsigned int r = (u + 0x7fffu + ((u >> 16) & 1u)) >> 16;
    return (unsigned short)r;
}

static __device__ __forceinline__ float fast_sigmoid(float y){
    return __builtin_amdgcn_rcpf(1.0f + __expf(-y));
}

static __device__ __forceinline__ bf16x8 ldfrag(const unsigned short* p){
    return __builtin_bit_cast(bf16x8, *(const short8*)(p));
}

// pack two f32 -> (bf16 lo, bf16 hi) by truncation: one v_perm_b32
static __device__ __forceinline__ unsigned packtrunc(float lo, float hi){
    return __builtin_amdgcn_perm(__float_as_uint(hi), __float_as_uint(lo), 0x07060302u);
}

#define MF(A,B,C) __builtin_amdgcn_mfma_f32_16x16x32_bf16((A),(B),(C),0,0,0)

// blocks 0..63: H f32 -> Hb bf16 (1024x64); block 64/65: W/Wa -> Wt[j][k] bf16
__global__ void prep(const float* __restrict__ H, const float* __restrict__ W,
                     const float* __restrict__ Wa,
                     unsigned short* __restrict__ Hb,
                     unsigned short* __restrict__ WtE,
                     unsigned short* __restrict__ WtA){
    int bid = blockIdx.x, tid = threadIdx.x;
    if (bid < 64){
        int i = (bid*256 + tid)*4;
        float4 v = *(const float4*)(H + i);
        ushort4 o;
        o.x = f2b(v.x); o.y = f2b(v.y); o.z = f2b(v.z); o.w = f2b(v.w);
        *(ushort4*)(Hb + i) = o;
    } else {
        const float* src = (bid == 64) ? W : Wa;
        unsigned short* dst = (bid == 64) ? WtE : WtA;
        for (int idx = tid; idx < FIN*FN; idx += 256){
            int k = idx >> 6, j = idx & 63;
            dst[j*FIN + k] = f2b(src[idx]);
        }
    }
}

// Stage tile su (64 E-rows, 8KB f32) into Et[buf_]. Physical LDS chunk
// L = is*256 + tid holds logical chunk decoded as:
//   c=L&15 (col/row-in-16), q=(L>>4)&3 (quad), s=(L>>6)&1 (lo/hi 16B),
//   mt=(L>>7)&1, mh=(L>>8)&1; row = mh*32+mt*16+c; floats = row*32+(q*2+s)*4.
// => COMPMT's ds_read_b128 for (mh,mt,s) reads 64 consecutive chunks at
//    base+lane*16: conflict-free. Dest base is wave-uniform; HW adds lane*16.
#define STAGE(buf_, su_) do {                                               \
    const float* gt_ = E + (size_t)a*(NN*FE) + (su_)*2048;                  \
    _Pragma("unroll")                                                       \
    for (int is_ = 0; is_ < 2; is_++){                                      \
        int L_   = is_*256 + tid;                                           \
        int row_ = ((L_>>8)&1)*32 + ((L_>>7)&1)*16 + (L_ & 15);             \
        int src_ = row_*32 + ((((L_>>4)&3)*2 + ((L_>>6)&1))*4);             \
        __builtin_amdgcn_global_load_lds(                                   \
            (gu32*)(gt_ + src_),                                            \
            (lu32*)(&Et[buf_][is_*1024 + wave*256]), 16, 0, 0);             \
    }                                                                       \
} while(0)

// One m-tile of one staged tile: 2 free ds_read_b128 (E), 2 L2-hot H loads,
// pack, 2x3 MFMA, gate+mask.
#define COMPMT(buf_, su_, mt_) do {                                         \
    const float* tp_ = &Et[buf_][(mh*2 + (mt_))*512 + quad*64 + col*4];     \
    float4 v0_ = *(const float4*)(tp_);                                     \
    float4 v1_ = *(const float4*)(tp_ + 256);                               \
    int gr_ = (su_)*64 + mh*32 + (mt_)*16 + col;                            \
    bf16x8 hh0_ = ldfrag(Hb + gr_*FN + quad*8);                             \
    bf16x8 hh1_ = ldfrag(Hb + gr_*FN + 32 + quad*8);                        \
    int4 pk_;                                                               \
    pk_.x = (int)packtrunc(v0_.x, v0_.y);                                   \
    pk_.y = (int)packtrunc(v0_.z, v0_.w);                                   \
    pk_.z = (int)packtrunc(v1_.x, v1_.y);                                   \
    pk_.w = (int)packtrunc(v1_.z, v1_.w);                                   \
    bf16x8 ef_ = __builtin_bit_cast(bf16x8, pk_);                           \
    _Pragma("unroll")                                                       \
    for (int tl = 0; tl < 2; tl++){                                         \
        f32x4 pw_ = MF(ef_, Bw[tl][2], MF(hh1_, Bw[tl][1],                  \
                     MF(hh0_, Bw[tl][0], cw[tl])));                         \
        f32x4 pa_ = MF(ef_, Ba[tl][2], MF(hh1_, Ba[tl][1],                  \
                     MF(hh0_, Ba[tl][0], ca[tl])));                         \
        _Pragma("unroll")                                                   \
        for (int r4 = 0; r4 < 4; r4++){                                     \
            float am_ = amask[(su_)*64 + mh*32 + (mt_)*16 + quad*4 + r4];   \
            float f_  = fmaxf(pw_[r4], 0.f) * fast_sigmoid(pa_[r4]);        \
            acc[tl] += am_ * f_;                                            \
        }                                                                   \
    }                                                                       \
} while(0)

// One block per row a. Stream all 1024 b-rows of E[a] through double-
// buffered LDS tiles; mask gate with A[a,b] from LDS; write out[a,:]
// directly including the (N-c1)*g0 constant term.
// 4 waves, wave=(half<<1)|mh: half -> j-tiles {2half,2half+1}, mh -> 32-row
// half of each 64-row tile.
// mfma_f32_16x16x32_bf16: A[m=lane&15][k=quad*8+i], B[k][n=lane&15],
// D: col=lane&15, row=quad*4+reg  [measured m89/m91].
__global__ __launch_bounds__(256, 4) void mga_fused(
    const float* __restrict__ A,
    const float* __restrict__ E,
    const unsigned short* __restrict__ Hb,
    const unsigned short* __restrict__ WtE, const unsigned short* __restrict__ WtA,
    const float* __restrict__ bias, float* __restrict__ out)
{
    int a    = blockIdx.x;
    int tid  = threadIdx.x;
    int wave = tid >> 6, lane = tid & 63;
    int col  = lane & 15, quad = lane >> 4;
    int half = wave >> 1, mh = wave & 1;

    __shared__ float Et[2][2048];          // 2 x 8KB staged E tiles
    __shared__ float amask[NN];            // A row as f32 (values are 0.0/1.0)
    __shared__ float red[16*FN];
    __shared__ int wsum[4];

    // ---- issue A-row load first: latency hides under B-frags + init MFMAs
    int b0 = wave*256 + lane*4;
    float4 av = *(const float4*)(A + (size_t)a*NN + b0);

    // Held B-frags: k-segs {64..96,96..128,128..160} x 2 j-tiles x 2 mats
    bf16x8 Bw[2][3], Ba[2][3];
    #pragma unroll
    for (int tl = 0; tl < 2; tl++){
        int n = (2*half + tl)*16 + col;
        #pragma unroll
        for (int sg = 0; sg < 3; sg++){
            Bw[tl][sg] = ldfrag(WtE + n*FIN + (sg+2)*32 + quad*8);
            Ba[tl][sg] = ldfrag(WtA + n*FIN + (sg+2)*32 + quad*8);
        }
    }

    // Upfront c-init = bias[j] + H[a]·W[0:64,j] via broadcast-A MFMAs
    bf16x8 ha0 = ldfrag(Hb + a*FN + quad*8);
    bf16x8 ha1 = ldfrag(Hb + a*FN + 32 + quad*8);
    f32x4 cw[2], ca[2];
    float acc[2] = {0.f, 0.f};
    #pragma unroll
    for (int tl = 0; tl < 2; tl++){
        int n = (2*half + tl)*16 + col;
        float bj = bias[n];
        f32x4 cb = {bj, bj, bj, bj};
        bf16x8 w0 = ldfrag(WtE + n*FIN + quad*8);
        bf16x8 w1 = ldfrag(WtE + n*FIN + 32 + quad*8);
        cw[tl] = MF(ha1, w1, MF(ha0, w0, cb));
        w0 = ldfrag(WtA + n*FIN + quad*8);
        w1 = ldfrag(WtA + n*FIN + 32 + quad*8);
        ca[tl] = MF(ha1, w1, MF(ha0, w0, cb));
    }

    // ---- publish A row to LDS + count nonzeros
    *(float4*)(amask + b0) = av;
    int m = 0;
    m += (av.x != 0.f) ? 1 : 0;
    m += (av.y != 0.f) ? 1 : 0;
    m += (av.z != 0.f) ? 1 : 0;
    m += (av.w != 0.f) ? 1 : 0;
    #pragma unroll
    for (int d = 1; d < 64; d <<= 1) m += __shfl_xor(m, d, 64);
    if (lane == 0) wsum[wave] = m;

    // ---- prologue stage of tile 0, then one barrier for everything
    STAGE(0, 0);
    __syncthreads();   // amask+wsum visible; tile 0 resident (vmcnt drained)
    int c1 = wsum[0] + wsum[1] + wsum[2] + wsum[3];

    // ---- 2-phase loop: stage(su+1) overlaps compute(su); 1 barrier/tile
    for (int su = 0; su < 16; su++){
        int buf = su & 1;
        if (su < 15) STAGE(buf ^ 1, su + 1);
        COMPMT(buf, su, 0);
        COMPMT(buf, su, 1);
        __syncthreads();   // next tile resident + current buffer consumed
    }

    #pragma unroll
    for (int tl = 0; tl < 2; tl++)
        red[(wave*4 + quad)*FN + (2*half + tl)*16 + col] = acc[tl];
    __syncthreads();
    if (tid < FN){
        int rbase = (tid >= 32) ? 8 : 0;   // waves 0,1: j<32; waves 2,3: j>=32
        float sum = 0.f;
        #pragma unroll
        for (int r = 0; r < 8; r++) sum += red[(rbase + r)*FN + tid];
        float bj = bias[tid];
        float g0 = fmaxf(bj, 0.f) * fast_sigmoid(bj);
        out[(size_t)a*FN + tid] = sum + (float)(NN - c1) * g0;
    }
}

extern "C" void kernel_launch(void* const* d_in, const int* in_sizes, int n_in,
                              void* d_out, int out_size, void* d_ws, size_t ws_size,
                              hipStream_t stream) {
    const float* H    = (const float*)d_in[0];
    const float* A    = (const float*)d_in[1];
    const float* E    = (const float*)d_in[2];
    const float* W    = (const float*)d_in[3];
    const float* Wa   = (const float*)d_in[4];
    const float* bias = (const float*)d_in[5];
    float* out = (float*)d_out;

    unsigned short* Hb   = (unsigned short*)d_ws;         // 1024*64 bf16
    unsigned short* WtE  = Hb + NN*FN;                    // 64*160
    unsigned short* WtA  = WtE + FN*FIN;                  // 64*160

    prep     <<<dim3(66), dim3(256), 0, stream>>>(H, W, Wa, Hb, WtE, WtA);
    mga_fused<<<dim3(NN), dim3(256), 0, stream>>>(A, E, Hb, WtE, WtA, bias, out);
}

// Round 9
// 232.994 us; speedup vs baseline: 1.6072x; 1.0211x over previous
//
#include <hip/hip_runtime.h>

// N=1024, F_NODE=64, F_EDGE=32, F_IN=160.
// out[a,j] = sum_b gated(a,b,j);  gated = relu(Hp)*sigmoid(Ha)
// Hp[a,b,j] = A[a,b]*(H[a]·W[0:64,j] + H[b]·W[64:128,j] + E[a,b]·W[128:160,j]) + bias[j]
// A in {0,1}: A=0 pairs contribute g0[j]=relu(bias)*sigmoid(bias) (constant).
//
// R17 (this round): counted vmcnt + raw s_barrier (T4), quad-buffered.
//  - R16 was clean (no scratch) but drain-paced: __syncthreads per tile =
//    s_waitcnt vmcnt(0) -> prefetch depth 0, 78us with nothing saturated
//    (HBM 11%, MFMA 13%, VALU 29%).
//  - Now: 4 LDS buffers; iter su: STAGE(su+2); s_waitcnt vmcnt(4) (own
//    outstanding = stages su+1,su+2; tile su landed); raw s_barrier;
//    compute(su). Stages stay in flight ACROSS barriers (m201/m218 recipe).
//    Tail peels vmcnt(2)/vmcnt(0). All waits are per-wave own-counts; the
//    barrier promotes them to block-wide guarantees.
//  - WAR-safe: stage(su+2) writes buf (su-2)%4, last read before barrier
//    su-1; max wave skew is one iteration (single barrier per iter).
//  - red[] aliases Et (last Et[0] read is 3 barriers before red writes).
//    LDS 36.9KB -> still 4 blocks/CU.
//  - Unchanged from R16: global_load_lds DMA staging, permuted
//    conflict-free layout, A-mask from LDS, transient L2-hot H loads,
//    (N-c1)*g0 constant path, no setprio.
#define NN 1024
#define FN 64
#define FE 32
#define FIN 160

#pragma clang diagnostic ignored "-Waddress-space-conversion"

typedef __bf16 bf16x8 __attribute__((ext_vector_type(8)));
typedef short  short8 __attribute__((ext_vector_type(8)));
typedef float  f32x4  __attribute__((ext_vector_type(4)));
typedef __attribute__((address_space(1))) const unsigned int gu32;
typedef __attribute__((address_space(3))) unsigned int lu32;

static __device__ __forceinline__ unsigned short f2b(float x){
    unsigned int u = __float_as_uint(x);
    unsigned int r = (u + 0x7fffu + ((u >> 16) & 1u)) >> 16;
    return (unsigned short)r;
}

static __device__ __forceinline__ float fast_sigmoid(float y){
    return __builtin_amdgcn_rcpf(1.0f + __expf(-y));
}

static __device__ __forceinline__ bf16x8 ldfrag(const unsigned short* p){
    return __builtin_bit_cast(bf16x8, *(const short8*)(p));
}

// pack two f32 -> (bf16 lo, bf16 hi) by truncation: one v_perm_b32
static __device__ __forceinline__ unsigned packtrunc(float lo, float hi){
    return __builtin_amdgcn_perm(__float_as_uint(hi), __float_as_uint(lo), 0x07060302u);
}

#define MF(A,B,C) __builtin_amdgcn_mfma_f32_16x16x32_bf16((A),(B),(C),0,0,0)

// blocks 0..63: H f32 -> Hb bf16 (1024x64); block 64/65: W/Wa -> Wt[j][k] bf16
__global__ void prep(const float* __restrict__ H, const float* __restrict__ W,
                     const float* __restrict__ Wa,
                     unsigned short* __restrict__ Hb,
                     unsigned short* __restrict__ WtE,
                     unsigned short* __restrict__ WtA){
    int bid = blockIdx.x, tid = threadIdx.x;
    if (bid < 64){
        int i = (bid*256 + tid)*4;
        float4 v = *(const float4*)(H + i);
        ushort4 o;
        o.x = f2b(v.x); o.y = f2b(v.y); o.z = f2b(v.z); o.w = f2b(v.w);
        *(ushort4*)(Hb + i) = o;
    } else {
        const float* src = (bid == 64) ? W : Wa;
        unsigned short* dst = (bid == 64) ? WtE : WtA;
        for (int idx = tid; idx < FIN*FN; idx += 256){
            int k = idx >> 6, j = idx & 63;
            dst[j*FIN + k] = f2b(src[idx]);
        }
    }
}

// Stage tile su (64 E-rows, 8KB f32) into Et[buf_]. Physical LDS chunk
// L = is*256 + tid holds logical chunk decoded as:
//   c=L&15, q=(L>>4)&3, s=(L>>6)&1, mt=(L>>7)&1, mh=(L>>8)&1;
//   row = mh*32+mt*16+c; float offset = row*32+(q*2+s)*4.
// => COMPMT's ds_read_b128 reads 64 consecutive chunks at base+lane*16:
//    conflict-free. LDS dest base wave-uniform; HW adds lane*16.
// Per wave: 2 gload_lds vmem ops (this is the vmcnt currency).
#define STAGE(buf_, su_) do {                                               \
    const float* gt_ = E + (size_t)a*(NN*FE) + (su_)*2048;                  \
    _Pragma("unroll")                                                       \
    for (int is_ = 0; is_ < 2; is_++){                                      \
        int L_   = is_*256 + tid;                                           \
        int row_ = ((L_>>8)&1)*32 + ((L_>>7)&1)*16 + (L_ & 15);             \
        int src_ = row_*32 + ((((L_>>4)&3)*2 + ((L_>>6)&1))*4);             \
        __builtin_amdgcn_global_load_lds(                                   \
            (gu32*)(gt_ + src_),                                            \
            (lu32*)(&Et[buf_][is_*1024 + wave*256]), 16, 0, 0);             \
    }                                                                       \
} while(0)

// One m-tile of one staged tile: 2 conflict-free ds_read_b128 (E),
// 2 L2-hot H loads, pack, 2x3 MFMA x2, gate+mask.
#define COMPMT(buf_, su_, mt_) do {                                         \
    const float* tp_ = &Et[buf_][(mh*2 + (mt_))*512 + quad*64 + col*4];     \
    float4 v0_ = *(const float4*)(tp_);                                     \
    float4 v1_ = *(const float4*)(tp_ + 256);                               \
    int gr_ = (su_)*64 + mh*32 + (mt_)*16 + col;                            \
    bf16x8 hh0_ = ldfrag(Hb + gr_*FN + quad*8);                             \
    bf16x8 hh1_ = ldfrag(Hb + gr_*FN + 32 + quad*8);                        \
    int4 pk_;                                                               \
    pk_.x = (int)packtrunc(v0_.x, v0_.y);                                   \
    pk_.y = (int)packtrunc(v0_.z, v0_.w);                                   \
    pk_.z = (int)packtrunc(v1_.x, v1_.y);                                   \
    pk_.w = (int)packtrunc(v1_.z, v1_.w);                                   \
    bf16x8 ef_ = __builtin_bit_cast(bf16x8, pk_);                           \
    _Pragma("unroll")                                                       \
    for (int tl = 0; tl < 2; tl++){                                         \
        f32x4 pw_ = MF(ef_, Bw[tl][2], MF(hh1_, Bw[tl][1],                  \
                     MF(hh0_, Bw[tl][0], cw[tl])));                         \
        f32x4 pa_ = MF(ef_, Ba[tl][2], MF(hh1_, Ba[tl][1],                  \
                     MF(hh0_, Ba[tl][0], ca[tl])));                         \
        _Pragma("unroll")                                                   \
        for (int r4 = 0; r4 < 4; r4++){                                     \
            float am_ = amask[(su_)*64 + mh*32 + (mt_)*16 + quad*4 + r4];   \
            float f_  = fmaxf(pw_[r4], 0.f) * fast_sigmoid(pa_[r4]);        \
            acc[tl] += am_ * f_;                                            \
        }                                                                   \
    }                                                                       \
} while(0)

// One block per row a. Stream all 1024 b-rows of E[a] through quad-
// buffered LDS tiles with counted-vmcnt pipelining.
// 4 waves, wave=(half<<1)|mh: half -> j-tiles {2half,2half+1}, mh -> 32-row
// half of each 64-row tile.
// mfma_f32_16x16x32_bf16: A[m=lane&15][k=quad*8+i], B[k][n=lane&15],
// D: col=lane&15, row=quad*4+reg  [measured m89/m91].
__global__ __launch_bounds__(256, 4) void mga_fused(
    const float* __restrict__ A,
    const float* __restrict__ E,
    const unsigned short* __restrict__ Hb,
    const unsigned short* __restrict__ WtE, const unsigned short* __restrict__ WtA,
    const float* __restrict__ bias, float* __restrict__ out)
{
    int a    = blockIdx.x;
    int tid  = threadIdx.x;
    int wave = tid >> 6, lane = tid & 63;
    int col  = lane & 15, quad = lane >> 4;
    int half = wave >> 1, mh = wave & 1;

    __shared__ float Et[4][2048];          // 4 x 8KB staged E tiles (32KB)
    __shared__ float amask[NN];            // A row as f32 (values are 0.0/1.0)
    __shared__ int wsum[4];
    float* red = (float*)Et;               // aliased: red used only after loop

    // ---- issue A-row load first: latency hides under B-frags + init MFMAs
    int b0 = wave*256 + lane*4;
    float4 av = *(const float4*)(A + (size_t)a*NN + b0);

    // Held B-frags: k-segs {64..96,96..128,128..160} x 2 j-tiles x 2 mats
    bf16x8 Bw[2][3], Ba[2][3];
    #pragma unroll
    for (int tl = 0; tl < 2; tl++){
        int n = (2*half + tl)*16 + col;
        #pragma unroll
        for (int sg = 0; sg < 3; sg++){
            Bw[tl][sg] = ldfrag(WtE + n*FIN + (sg+2)*32 + quad*8);
            Ba[tl][sg] = ldfrag(WtA + n*FIN + (sg+2)*32 + quad*8);
        }
    }

    // Upfront c-init = bias[j] + H[a]·W[0:64,j] via broadcast-A MFMAs
    bf16x8 ha0 = ldfrag(Hb + a*FN + quad*8);
    bf16x8 ha1 = ldfrag(Hb + a*FN + 32 + quad*8);
    f32x4 cw[2], ca[2];
    float acc[2] = {0.f, 0.f};
    #pragma unroll
    for (int tl = 0; tl < 2; tl++){
        int n = (2*half + tl)*16 + col;
        float bj = bias[n];
        f32x4 cb = {bj, bj, bj, bj};
        bf16x8 w0 = ldfrag(WtE + n*FIN + quad*8);
        bf16x8 w1 = ldfrag(WtE + n*FIN + 32 + quad*8);
        cw[tl] = MF(ha1, w1, MF(ha0, w0, cb));
        w0 = ldfrag(WtA + n*FIN + quad*8);
        w1 = ldfrag(WtA + n*FIN + 32 + quad*8);
        ca[tl] = MF(ha1, w1, MF(ha0, w0, cb));
    }

    // ---- publish A row to LDS + count nonzeros
    *(float4*)(amask + b0) = av;
    int m = 0;
    m += (av.x != 0.f) ? 1 : 0;
    m += (av.y != 0.f) ? 1 : 0;
    m += (av.z != 0.f) ? 1 : 0;
    m += (av.w != 0.f) ? 1 : 0;
    #pragma unroll
    for (int d = 1; d < 64; d <<= 1) m += __shfl_xor(m, d, 64);
    if (lane == 0) wsum[wave] = m;

    // ---- prologue: stage tiles 0,1; ONE full drain (amask+wsum+tiles 0,1)
    STAGE(0, 0);
    STAGE(1, 1);
    __syncthreads();
    int c1 = wsum[0] + wsum[1] + wsum[2] + wsum[3];

    // ---- counted-vmcnt pipeline: one raw barrier per tile, loads in
    // flight across it. Steady state outstanding at wait = 4 (2 stages).
    #pragma unroll
    for (int su = 0; su < 16; su++){
        int buf = su & 3;
        if (su + 2 < 16) STAGE((su + 2) & 3, su + 2);
        if (su < 14)      { asm volatile("s_waitcnt vmcnt(4)" ::: "memory"); }
        else if (su == 14){ asm volatile("s_waitcnt vmcnt(2)" ::: "memory"); }
        else              { asm volatile("s_waitcnt vmcnt(0)" ::: "memory"); }
        __builtin_amdgcn_s_barrier();      // tile su resident block-wide
        COMPMT(buf, su, 0);
        COMPMT(buf, su, 1);
    }

    // red aliases Et[0..1]: all waves are past the iter-13 barrier here, so
    // every compute(<=12) (last Et[0] readers) has finished. Writes are to
    // each thread's own slot; barrier below orders writes vs reads.
    #pragma unroll
    for (int tl = 0; tl < 2; tl++)
        red[(wave*4 + quad)*FN + (2*half + tl)*16 + col] = acc[tl];
    __syncthreads();
    if (tid < FN){
        int rbase = (tid >= 32) ? 8 : 0;   // waves 0,1: j<32; waves 2,3: j>=32
        float sum = 0.f;
        #pragma unroll
        for (int r = 0; r < 8; r++) sum += red[(rbase + r)*FN + tid];
        float bj = bias[tid];
        float g0 = fmaxf(bj, 0.f) * fast_sigmoid(bj);
        out[(size_t)a*FN + tid] = sum + (float)(NN - c1) * g0;
    }
}

extern "C" void kernel_launch(void* const* d_in, const int* in_sizes, int n_in,
                              void* d_out, int out_size, void* d_ws, size_t ws_size,
                              hipStream_t stream) {
    const float* H    = (const float*)d_in[0];
    const float* A    = (const float*)d_in[1];
    const float* E    = (const float*)d_in[2];
    const float* W    = (const float*)d_in[3];
    const float* Wa   = (const float*)d_in[4];
    const float* bias = (const float*)d_in[5];
    float* out = (float*)d_out;

    unsigned short* Hb   = (unsigned short*)d_ws;         // 1024*64 bf16
    unsigned short* WtE  = Hb + NN*FN;                    // 64*160
    unsigned short* WtA  = WtE + FN*FIN;                  // 64*160

    prep     <<<dim3(66), dim3(256), 0, stream>>>(H, W, Wa, Hb, WtE, WtA);
    mga_fused<<<dim3(NN), dim3(256), 0, stream>>>(A, E, Hb, WtE, WtA, bias, out);
}